// Round 13
// baseline (87.732 us; speedup 1.0000x reference)
//
#include <hip/hip_runtime.h>
#include <hip/hip_bf16.h>
#include <cstdint>

#define B_ 8
#define C_ 128
#define N_ 16384   // H*W
#define CHN 512    // n per KA block
#define SN 128     // n per subtile
#define NST 4      // subtiles per KA block
#define NC (N_ / CHN)  // 32 chunks

typedef __attribute__((ext_vector_type(8))) short short8;
typedef __attribute__((ext_vector_type(4))) float f32x4;
typedef __attribute__((ext_vector_type(4))) unsigned short us4;
typedef unsigned short u16;

__device__ __forceinline__ short f2bf(float f) {
  union { float f; unsigned u; } c; c.f = f;
  unsigned r = (c.u + 0x7FFFu + ((c.u >> 16) & 1u)) >> 16;
  return (short)r;
}

__device__ __forceinline__ unsigned cvtpk(float lo, float hi) {
  unsigned r;
  asm("v_cvt_pk_bf16_f32 %0, %1, %2" : "=v"(r) : "v"(lo), "v"(hi));
  return r;
}

union SB { short8 s8; unsigned u[4]; };

// ---------------------------------------------------------------------------
// K0: preconvert k_w, v_w (fp32) -> wbf (bf16 [2][128][128])
// ---------------------------------------------------------------------------
__global__ __launch_bounds__(256) void k0_wcvt(const float* __restrict__ kw,
                                               const float* __restrict__ vw,
                                               u16* __restrict__ wbf) {
  const int g = blockIdx.x * 256 + threadIdx.x;  // 0..8191 float4s
  const int mat = g >> 12, o4 = g & 4095;
  const float* src = mat ? vw : kw;
  float4 f = reinterpret_cast<const float4*>(src)[o4];
  us4 s;
  s[0] = (u16)f2bf(f.x); s[1] = (u16)f2bf(f.y);
  s[2] = (u16)f2bf(f.z); s[3] = (u16)f2bf(f.w);
  reinterpret_cast<us4*>(wbf + (size_t)mat * C_ * C_)[o4] = s;
}

// ---------------------------------------------------------------------------
// KA: fused projection + context partial (rounds 6-12 core, passed 0.03125)
// with chunked XCD remap (XCD k owns batch k).
// ---------------------------------------------------------------------------
#define KA_LOADS(ST_) do {                                                   \
  _Pragma("unroll") for (int h_ = 0; h_ < 2; ++h_)                           \
  _Pragma("unroll") for (int j_ = 0; j_ < 16; ++j_)                          \
    xr[h_][j_] = xw[(size_t)j_ * N_ + (ST_) * SN + h_ * 64 + lane];          \
} while (0)

#define KA_XWRITE(BUF_) do {                                                 \
  _Pragma("unroll") for (int h_ = 0; h_ < 2; ++h_) {                         \
    const int n_ = h_ * 64 + lane;                                           \
    unsigned pk_[8];                                                         \
    _Pragma("unroll") for (int p_ = 0; p_ < 8; ++p_)                         \
      pk_[p_] = cvtpk(xr[h_][2 * p_], xr[h_][2 * p_ + 1]);                   \
    _Pragma("unroll") for (int o_ = 0; o_ < 2; ++o_) {                       \
      uint4 q_;                                                              \
      q_.x = pk_[o_ * 4]; q_.y = pk_[o_ * 4 + 1];                            \
      q_.z = pk_[o_ * 4 + 2]; q_.w = pk_[o_ * 4 + 3];                        \
      *reinterpret_cast<uint4*>(                                             \
          (BUF_) + n_ * SN + ((w * 16 + o_ * 8) ^ ((n_ & 7) << 3))) = q_;    \
    }                                                                        \
  }                                                                          \
} while (0)

__global__ __launch_bounds__(512, 2) void ka_projctx(
    const float* __restrict__ kv, const u16* __restrict__ wbf,
    const float* __restrict__ kb, const float* __restrict__ vb,
    float* __restrict__ part, float* __restrict__ zpart) {
  __shared__ u16 xt[2][C_ * SN];   // 2 x 32 KB transposed bf16 x
  __shared__ u16 eks[C_ * SN];     // 32 KB EK stash [d][n]
  __shared__ u16 vs [C_ * SN];     // 32 KB V  stash [c][n]

  const int fid = blockIdx.x + blockIdx.y * NC;
  const int fid2 = (fid & 7) * 32 + (fid >> 3);  // XCD k -> batch k
  const int b = fid2 >> 5, kc = fid2 & 31;
  const int tid = threadIdx.x;
  const int w = tid >> 6, lane = tid & 63;
  const int lg = lane >> 4, li = lane & 15;
  const int mat = w >> 2, dblk = w & 3;
  const int cg = w >> 1, dh = w & 1;

  const float* xb = kv + (size_t)b * C_ * N_ + (size_t)kc * CHN;
  const float* xw = xb + (size_t)(w * 16) * N_;  // wave's 16 c-rows
  const u16* Wm = wbf + (size_t)mat * C_ * C_;
  const float* biasp = mat ? vb : kb;
  u16* S = mat ? vs : eks;

  short8 wreg[2][4];
#pragma unroll
  for (int dt = 0; dt < 2; ++dt)
#pragma unroll
    for (int ks = 0; ks < 4; ++ks)
      wreg[dt][ks] = *reinterpret_cast<const short8*>(
          Wm + (dblk * 32 + dt * 16 + li) * C_ + ks * 32 + lg * 8);
  float bias2[2];
#pragma unroll
  for (int dt = 0; dt < 2; ++dt) bias2[dt] = biasp[dblk * 32 + dt * 16 + li];

  f32x4 acc[2][4] = {};   // ctx accumulator [am c][dt d]
  float zac[2] = {0.f, 0.f};
  float xr[2][16];        // reg-staged x: [n-half][c-row j]

  KA_LOADS(0);
  KA_XWRITE(&xt[0][0]);
  KA_LOADS(1);
  asm volatile("s_waitcnt lgkmcnt(0)" ::: "memory");
  __builtin_amdgcn_s_barrier();
  __builtin_amdgcn_sched_barrier(0);

#pragma unroll
  for (int st = 0; st < NST; ++st) {
    const u16* xc = &xt[st & 1][0];

    if (st < NST - 1) {
      KA_XWRITE(&xt[(st + 1) & 1][0]);
      if (st < NST - 2) KA_LOADS(st + 2);
    }

    // ---- proj: D[n][d] = xT · W^T, in nt-pairs ----
#pragma unroll
    for (int h2 = 0; h2 < 4; ++h2) {
      f32x4 pacc[2][2] = {};  // [ntl][dt]
#pragma unroll
      for (int ntl = 0; ntl < 2; ++ntl) {
        const int n = (h2 * 2 + ntl) * 16 + li;
#pragma unroll
        for (int ks = 0; ks < 4; ++ks) {
          short8 a = *reinterpret_cast<const short8*>(
              xc + n * SN + ((ks * 32 + lg * 8) ^ ((n & 7) << 3)));
#pragma unroll
          for (int dt = 0; dt < 2; ++dt)
            pacc[ntl][dt] = __builtin_amdgcn_mfma_f32_16x16x32_bf16(
                a, wreg[dt][ks], pacc[ntl][dt], 0, 0, 0);
        }
      }
#pragma unroll
      for (int dt = 0; dt < 2; ++dt) {
        const int d = dblk * 32 + dt * 16 + li;
        const float bias = bias2[dt];
#pragma unroll
        for (int ntl = 0; ntl < 2; ++ntl) {
          float v0 = pacc[ntl][dt][0] + bias;
          float v1 = pacc[ntl][dt][1] + bias;
          float v2 = pacc[ntl][dt][2] + bias;
          float v3 = pacc[ntl][dt][3] + bias;
          if (mat == 0) {
            v0 = __expf(v0); v1 = __expf(v1); v2 = __expf(v2); v3 = __expf(v3);
            zac[dt] += (v0 + v1) + (v2 + v3);
          }
          const int nq = (h2 * 2 + ntl) * 16 + lg * 4;
          uint2 pk; pk.x = cvtpk(v0, v1); pk.y = cvtpk(v2, v3);
          *reinterpret_cast<uint2*>(S + d * SN + (nq ^ ((d & 7) << 3))) = pk;
        }
      }
    }
    asm volatile("s_waitcnt lgkmcnt(0)" ::: "memory");
    __builtin_amdgcn_s_barrier();
    __builtin_amdgcn_sched_barrier(0);

    // ---- ctx: part += V·EK^T over this subtile's 128 n ----
#pragma unroll
    for (int kk = 0; kk < 4; ++kk) {
      const int n0 = kk * 32 + lg * 8;
      short8 a[2], bb[4];
#pragma unroll
      for (int am = 0; am < 2; ++am) {
        const int c = cg * 32 + am * 16 + li;
        a[am] = *reinterpret_cast<const short8*>(vs + c * SN + (n0 ^ ((c & 7) << 3)));
      }
#pragma unroll
      for (int dt = 0; dt < 4; ++dt) {
        const int d = dh * 64 + dt * 16 + li;
        bb[dt] = *reinterpret_cast<const short8*>(eks + d * SN + (n0 ^ ((d & 7) << 3)));
      }
#pragma unroll
      for (int am = 0; am < 2; ++am)
#pragma unroll
        for (int dt = 0; dt < 4; ++dt)
          acc[am][dt] = __builtin_amdgcn_mfma_f32_16x16x32_bf16(a[am], bb[dt], acc[am][dt], 0, 0, 0);
    }
    asm volatile("s_waitcnt lgkmcnt(0)" ::: "memory");
    __builtin_amdgcn_s_barrier();
    __builtin_amdgcn_sched_barrier(0);
  }

  // ---- epilogue: part + zpart (deterministic, no atomics) ----
  float* P = part + ((size_t)kc * B_ + b) * C_ * C_;
#pragma unroll
  for (int am = 0; am < 2; ++am)
#pragma unroll
    for (int dt = 0; dt < 4; ++dt)
#pragma unroll
      for (int r = 0; r < 4; ++r) {
        const int c = cg * 32 + am * 16 + lg * 4 + r;
        const int d = dh * 64 + dt * 16 + li;
        P[c * C_ + d] = acc[am][dt][r];
      }
  if (mat == 0) {
#pragma unroll
    for (int dt = 0; dt < 2; ++dt) {
      float z = zac[dt];
      z += __shfl_xor(z, 16);
      z += __shfl_xor(z, 32);
      if (lg == 0)
        zpart[((size_t)kc * B_ + b) * C_ + dblk * 32 + dt * 16 + li] = z;
    }
  }
}

// ---------------------------------------------------------------------------
// KB2: cs = (sum_kc part)/Z ; M = cs·qw (bf16), T = cs·qb
// (unchanged from rounds 8-12)
// ---------------------------------------------------------------------------
__global__ __launch_bounds__(256) void kb2_fin(
    const float* __restrict__ part, const float* __restrict__ zpart,
    const float* __restrict__ qw, const float* __restrict__ qb,
    u16* __restrict__ M, float* __restrict__ T) {
  const int b = blockIdx.y;
  const int cs0 = blockIdx.x * 16;
  const int tid = threadIdx.x;
  __shared__ float cs[16][128];
  __shared__ float Zs[128];
  if (tid < 128) {
    float s = 0.f;
    for (int kc = 0; kc < NC; ++kc)
      s += zpart[((size_t)kc * B_ + b) * C_ + tid];
    Zs[tid] = s;
  }
  __syncthreads();
#pragma unroll
  for (int i = 0; i < 8; ++i) {
    const int e = tid + i * 256;
    const int cl = e >> 7, d = e & 127;
    float s = 0.f;
    for (int kc = 0; kc < NC; ++kc)
      s += part[(((size_t)kc * B_ + b) * C_ + (cs0 + cl)) * C_ + d];
    cs[cl][d] = s / Zs[d];
  }
  __syncthreads();
  const int cl = tid >> 4, e0 = (tid & 15) * 8;
  float m[8] = {};
  for (int d = 0; d < 128; ++d) {
    const float cv = cs[cl][d];
    const float* qr = qw + d * C_ + e0;
#pragma unroll
    for (int j = 0; j < 8; ++j) m[j] += cv * qr[j];
  }
  u16* mp = M + ((size_t)b * C_ + cs0 + cl) * C_ + e0;
#pragma unroll
  for (int j = 0; j < 8; ++j) mp[j] = (u16)f2bf(m[j]);
  if (tid < 16) {
    float tv = 0.f;
    for (int d = 0; d < 128; ++d) tv += cs[tid][d] * qb[d];
    T[b * C_ + cs0 + tid] = tv;
  }
}

// ---------------------------------------------------------------------------
// K4: out = M·q_feat + T (fp32).  grid 256 (1D, 1/CU), 512 thr = 8 waves.
// FAT-N TILING for write run-length: block owns [16 c][4096 n] -> each out
// row written as ONE sequential 16-KB run (vs <=2 KB in r6-r12, all ~41 µs).
// b = bid&7: dispatch round-robin puts batch b on XCD b; the 8 c-group
// blocks sharing a 2-MB q-slab run in lockstep on one XCD -> L2 hits;
// q fetched from HBM once.  32 double-buffered 128-n subtiles (KA pattern,
// lgkm-only barriers).  Per-output dot products bitwise-identical to r12
// (same fragments, same K order) -> absmax unchanged.
//   staging: wave w owns d-rows [w*16,+16), KA_LOADS/XWRITE forms
//   MFMA: wave w owns n-cols [w*16,+16), all 16 c; 4 MFMA/subtile
// ---------------------------------------------------------------------------
#define K4_LOADS(ST_) do {                                                   \
  _Pragma("unroll") for (int h_ = 0; h_ < 2; ++h_)                           \
  _Pragma("unroll") for (int j_ = 0; j_ < 16; ++j_)                          \
    xr[h_][j_] = qsrc[(size_t)j_ * N_ + (ST_) * SN + h_ * 64 + lane];        \
} while (0)

#define K4_XWRITE(BUF_) do {                                                 \
  _Pragma("unroll") for (int h_ = 0; h_ < 2; ++h_) {                         \
    const int n_ = h_ * 64 + lane;                                           \
    unsigned pk_[8];                                                         \
    _Pragma("unroll") for (int p_ = 0; p_ < 8; ++p_)                         \
      pk_[p_] = cvtpk(xr[h_][2 * p_], xr[h_][2 * p_ + 1]);                   \
    _Pragma("unroll") for (int o_ = 0; o_ < 2; ++o_) {                       \
      uint4 q_;                                                              \
      q_.x = pk_[o_ * 4]; q_.y = pk_[o_ * 4 + 1];                            \
      q_.z = pk_[o_ * 4 + 2]; q_.w = pk_[o_ * 4 + 3];                        \
      *reinterpret_cast<uint4*>(                                             \
          (BUF_) + n_ * SN + ((w * 16 + o_ * 8) ^ ((n_ & 7) << 3))) = q_;    \
    }                                                                        \
  }                                                                          \
} while (0)

#define K4_BODY(CUR_, ST_) do {                                              \
  f32x4 acc = {};                                                            \
  const int n_ = w * 16 + li;                                                \
  _Pragma("unroll") for (int ks_ = 0; ks_ < 4; ++ks_) {                      \
    short8 bb_ = *reinterpret_cast<const short8*>(                           \
        (CUR_) + n_ * SN + ((ks_ * 32 + lg * 8) ^ ((n_ & 7) << 3)));         \
    acc = __builtin_amdgcn_mfma_f32_16x16x32_bf16(mreg[ks_], bb_, acc, 0, 0, 0); \
  }                                                                          \
  _Pragma("unroll") for (int r_ = 0; r_ < 4; ++r_) {                         \
    const int c_ = cgrp * 16 + lg * 4 + r_;                                  \
    out[((size_t)b * C_ + c_) * N_ + nbase + (ST_) * SN + w * 16 + li] =     \
        acc[r_] + tcv[r_];                                                   \
  }                                                                          \
} while (0)

__global__ __launch_bounds__(512) void k4_out(const u16* __restrict__ M,
                                              const float* __restrict__ T,
                                              const float* __restrict__ q,
                                              float* __restrict__ out) {
  __shared__ u16 qt0[SN * C_];  // [n][d] bf16 swizzled, 32 KB
  __shared__ u16 qt1[SN * C_];  // double buffer, 32 KB

  const int bid = blockIdx.x;          // [0,256)
  const int b = bid & 7;               // XCD k -> batch k (round-robin)
  const int j = bid >> 3;              // [0,32)
  const int cgrp = j & 7;              // 8 c-groups of 16 rows
  const int nslab = j >> 3;            // 4 n-slabs of 4096
  const int nbase = nslab * 4096;
  const int tid = threadIdx.x;
  const int w = tid >> 6, lane = tid & 63;
  const int lg = lane >> 4, li = lane & 15;

  // staging source: wave w owns d-rows [w*16, +16) of q[b], n window nbase+
  const float* qsrc = q + (size_t)b * C_ * N_ + nbase + (size_t)(w * 16) * N_;

  // M fragments (A operand rows c = cgrp*16+li) + T (rows c = cgrp*16+lg*4+r)
  short8 mreg[4];
  const u16* Mb = M + (size_t)b * C_ * C_;
#pragma unroll
  for (int ks = 0; ks < 4; ++ks)
    mreg[ks] = *reinterpret_cast<const short8*>(
        Mb + (cgrp * 16 + li) * C_ + ks * 32 + lg * 8);
  float tcv[4];
#pragma unroll
  for (int r = 0; r < 4; ++r) tcv[r] = T[b * C_ + cgrp * 16 + lg * 4 + r];

  float xr[2][16];  // reg-staged q: [n-half][d-row j]

  // prologue
  K4_LOADS(0);
  K4_XWRITE(qt0);
  K4_LOADS(1);
  asm volatile("s_waitcnt lgkmcnt(0)" ::: "memory");
  __builtin_amdgcn_s_barrier();
  __builtin_amdgcn_sched_barrier(0);

  // 32 subtiles, unrolled by 2 for static buffer alternation
  for (int st2 = 0; st2 < 16; ++st2) {
    const int st = st2 * 2;
    // ---- even subtile: compute qt0, prep qt1/st+1, loads st+2 ----
    {
      K4_XWRITE(qt1);
      if (st < 30) K4_LOADS(st + 2);
      K4_BODY(qt0, st);
      asm volatile("s_waitcnt lgkmcnt(0)" ::: "memory");
      __builtin_amdgcn_s_barrier();
      __builtin_amdgcn_sched_barrier(0);
    }
    // ---- odd subtile: compute qt1, prep qt0/st+2, loads st+3 ----
    {
      if (st < 30) {
        K4_XWRITE(qt0);
        if (st < 29) K4_LOADS(st + 3);
      }
      K4_BODY(qt1, st + 1);
      asm volatile("s_waitcnt lgkmcnt(0)" ::: "memory");
      __builtin_amdgcn_s_barrier();
      __builtin_amdgcn_sched_barrier(0);
    }
  }
}

// ---------------------------------------------------------------------------
extern "C" void kernel_launch(void* const* d_in, const int* in_sizes, int n_in,
                              void* d_out, int out_size, void* d_ws, size_t ws_size,
                              hipStream_t stream) {
  const float* q_feat  = (const float*)d_in[0];
  const float* kv_feat = (const float*)d_in[1];
  const float* q_w = (const float*)d_in[2];
  const float* q_b = (const float*)d_in[3];
  const float* k_w = (const float*)d_in[4];
  const float* k_b = (const float*)d_in[5];
  const float* v_w = (const float*)d_in[6];
  const float* v_b = (const float*)d_in[7];
  float* out = (float*)d_out;

  char* ws = (char*)d_ws;
  const size_t szPart = (size_t)NC * B_ * C_ * C_ * sizeof(float);  // 16 MB
  const size_t szZp   = (size_t)NC * B_ * C_ * sizeof(float);       // 128 KB
  const size_t szWbf  = (size_t)2 * C_ * C_ * sizeof(u16);          // 64 KB
  const size_t szM    = (size_t)B_ * C_ * C_ * sizeof(u16);         // 256 KB

  float* part  = (float*)ws;
  float* zpart = (float*)(ws + szPart);
  u16*   wbf   = (u16*)(ws + szPart + szZp);
  u16*   M     = (u16*)(ws + szPart + szZp + szWbf);
  float* T     = (float*)(ws + szPart + szZp + szWbf + szM);

  k0_wcvt<<<dim3(32), 256, 0, stream>>>(k_w, v_w, wbf);
  ka_projctx<<<dim3(NC, B_), 512, 0, stream>>>(kv_feat, wbf, k_b, v_b, part, zpart);
  kb2_fin<<<dim3(8, B_), 256, 0, stream>>>(part, zpart, q_w, q_b, M, T);
  k4_out<<<dim3(256), 512, 0, stream>>>(M, T, q_feat, out);
}

// Round 14
// 76.464 us; speedup vs baseline: 1.1474x; 1.1474x over previous
//
#include <hip/hip_runtime.h>
#include <hip/hip_bf16.h>
#include <cstdint>

#define B_ 8
#define C_ 128
#define N_ 16384   // H*W
#define CHN 512    // n per block (KA and K4)
#define SN 128     // n per subtile
#define NST 4      // subtiles per block
#define NC (N_ / CHN)  // 32 chunks

typedef __attribute__((ext_vector_type(8))) short short8;
typedef __attribute__((ext_vector_type(4))) float f32x4;
typedef __attribute__((ext_vector_type(4))) unsigned short us4;
typedef unsigned short u16;

__device__ __forceinline__ short f2bf(float f) {
  union { float f; unsigned u; } c; c.f = f;
  unsigned r = (c.u + 0x7FFFu + ((c.u >> 16) & 1u)) >> 16;
  return (short)r;
}

__device__ __forceinline__ unsigned cvtpk(float lo, float hi) {
  unsigned r;
  asm("v_cvt_pk_bf16_f32 %0, %1, %2" : "=v"(r) : "v"(lo), "v"(hi));
  return r;
}

union SB { short8 s8; unsigned u[4]; };

// ---------------------------------------------------------------------------
// K0: preconvert k_w, v_w (fp32) -> wbf (bf16 [2][128][128])
// ---------------------------------------------------------------------------
__global__ __launch_bounds__(256) void k0_wcvt(const float* __restrict__ kw,
                                               const float* __restrict__ vw,
                                               u16* __restrict__ wbf) {
  const int g = blockIdx.x * 256 + threadIdx.x;  // 0..8191 float4s
  const int mat = g >> 12, o4 = g & 4095;
  const float* src = mat ? vw : kw;
  float4 f = reinterpret_cast<const float4*>(src)[o4];
  us4 s;
  s[0] = (u16)f2bf(f.x); s[1] = (u16)f2bf(f.y);
  s[2] = (u16)f2bf(f.z); s[3] = (u16)f2bf(f.w);
  reinterpret_cast<us4*>(wbf + (size_t)mat * C_ * C_)[o4] = s;
}

// ---------------------------------------------------------------------------
// KA: fused projection + context partial (rounds 6-12 core, passed 0.03125)
// with chunked XCD remap (XCD k owns batch k).  Writes deferred to epilogue
// (main loop is a pure read stream — this is why KA sustains ~4 TB/s).
// ---------------------------------------------------------------------------
#define KA_LOADS(ST_) do {                                                   \
  _Pragma("unroll") for (int h_ = 0; h_ < 2; ++h_)                           \
  _Pragma("unroll") for (int j_ = 0; j_ < 16; ++j_)                          \
    xr[h_][j_] = xw[(size_t)j_ * N_ + (ST_) * SN + h_ * 64 + lane];          \
} while (0)

#define KA_XWRITE(BUF_) do {                                                 \
  _Pragma("unroll") for (int h_ = 0; h_ < 2; ++h_) {                         \
    const int n_ = h_ * 64 + lane;                                           \
    unsigned pk_[8];                                                         \
    _Pragma("unroll") for (int p_ = 0; p_ < 8; ++p_)                         \
      pk_[p_] = cvtpk(xr[h_][2 * p_], xr[h_][2 * p_ + 1]);                   \
    _Pragma("unroll") for (int o_ = 0; o_ < 2; ++o_) {                       \
      uint4 q_;                                                              \
      q_.x = pk_[o_ * 4]; q_.y = pk_[o_ * 4 + 1];                            \
      q_.z = pk_[o_ * 4 + 2]; q_.w = pk_[o_ * 4 + 3];                        \
      *reinterpret_cast<uint4*>(                                             \
          (BUF_) + n_ * SN + ((w * 16 + o_ * 8) ^ ((n_ & 7) << 3))) = q_;    \
    }                                                                        \
  }                                                                          \
} while (0)

__global__ __launch_bounds__(512, 2) void ka_projctx(
    const float* __restrict__ kv, const u16* __restrict__ wbf,
    const float* __restrict__ kb, const float* __restrict__ vb,
    float* __restrict__ part, float* __restrict__ zpart) {
  __shared__ u16 xt[2][C_ * SN];   // 2 x 32 KB transposed bf16 x
  __shared__ u16 eks[C_ * SN];     // 32 KB EK stash [d][n]
  __shared__ u16 vs [C_ * SN];     // 32 KB V  stash [c][n]

  const int fid = blockIdx.x + blockIdx.y * NC;
  const int fid2 = (fid & 7) * 32 + (fid >> 3);  // XCD k -> batch k
  const int b = fid2 >> 5, kc = fid2 & 31;
  const int tid = threadIdx.x;
  const int w = tid >> 6, lane = tid & 63;
  const int lg = lane >> 4, li = lane & 15;
  const int mat = w >> 2, dblk = w & 3;
  const int cg = w >> 1, dh = w & 1;

  const float* xb = kv + (size_t)b * C_ * N_ + (size_t)kc * CHN;
  const float* xw = xb + (size_t)(w * 16) * N_;  // wave's 16 c-rows
  const u16* Wm = wbf + (size_t)mat * C_ * C_;
  const float* biasp = mat ? vb : kb;
  u16* S = mat ? vs : eks;

  short8 wreg[2][4];
#pragma unroll
  for (int dt = 0; dt < 2; ++dt)
#pragma unroll
    for (int ks = 0; ks < 4; ++ks)
      wreg[dt][ks] = *reinterpret_cast<const short8*>(
          Wm + (dblk * 32 + dt * 16 + li) * C_ + ks * 32 + lg * 8);
  float bias2[2];
#pragma unroll
  for (int dt = 0; dt < 2; ++dt) bias2[dt] = biasp[dblk * 32 + dt * 16 + li];

  f32x4 acc[2][4] = {};   // ctx accumulator [am c][dt d]
  float zac[2] = {0.f, 0.f};
  float xr[2][16];        // reg-staged x: [n-half][c-row j]

  KA_LOADS(0);
  KA_XWRITE(&xt[0][0]);
  KA_LOADS(1);
  asm volatile("s_waitcnt lgkmcnt(0)" ::: "memory");
  __builtin_amdgcn_s_barrier();
  __builtin_amdgcn_sched_barrier(0);

#pragma unroll
  for (int st = 0; st < NST; ++st) {
    const u16* xc = &xt[st & 1][0];

    if (st < NST - 1) {
      KA_XWRITE(&xt[(st + 1) & 1][0]);
      if (st < NST - 2) KA_LOADS(st + 2);
    }

    // ---- proj: D[n][d] = xT · W^T, in nt-pairs ----
#pragma unroll
    for (int h2 = 0; h2 < 4; ++h2) {
      f32x4 pacc[2][2] = {};  // [ntl][dt]
#pragma unroll
      for (int ntl = 0; ntl < 2; ++ntl) {
        const int n = (h2 * 2 + ntl) * 16 + li;
#pragma unroll
        for (int ks = 0; ks < 4; ++ks) {
          short8 a = *reinterpret_cast<const short8*>(
              xc + n * SN + ((ks * 32 + lg * 8) ^ ((n & 7) << 3)));
#pragma unroll
          for (int dt = 0; dt < 2; ++dt)
            pacc[ntl][dt] = __builtin_amdgcn_mfma_f32_16x16x32_bf16(
                a, wreg[dt][ks], pacc[ntl][dt], 0, 0, 0);
        }
      }
#pragma unroll
      for (int dt = 0; dt < 2; ++dt) {
        const int d = dblk * 32 + dt * 16 + li;
        const float bias = bias2[dt];
#pragma unroll
        for (int ntl = 0; ntl < 2; ++ntl) {
          float v0 = pacc[ntl][dt][0] + bias;
          float v1 = pacc[ntl][dt][1] + bias;
          float v2 = pacc[ntl][dt][2] + bias;
          float v3 = pacc[ntl][dt][3] + bias;
          if (mat == 0) {
            v0 = __expf(v0); v1 = __expf(v1); v2 = __expf(v2); v3 = __expf(v3);
            zac[dt] += (v0 + v1) + (v2 + v3);
          }
          const int nq = (h2 * 2 + ntl) * 16 + lg * 4;
          uint2 pk; pk.x = cvtpk(v0, v1); pk.y = cvtpk(v2, v3);
          *reinterpret_cast<uint2*>(S + d * SN + (nq ^ ((d & 7) << 3))) = pk;
        }
      }
    }
    asm volatile("s_waitcnt lgkmcnt(0)" ::: "memory");
    __builtin_amdgcn_s_barrier();
    __builtin_amdgcn_sched_barrier(0);

    // ---- ctx: part += V·EK^T over this subtile's 128 n ----
#pragma unroll
    for (int kk = 0; kk < 4; ++kk) {
      const int n0 = kk * 32 + lg * 8;
      short8 a[2], bb[4];
#pragma unroll
      for (int am = 0; am < 2; ++am) {
        const int c = cg * 32 + am * 16 + li;
        a[am] = *reinterpret_cast<const short8*>(vs + c * SN + (n0 ^ ((c & 7) << 3)));
      }
#pragma unroll
      for (int dt = 0; dt < 4; ++dt) {
        const int d = dh * 64 + dt * 16 + li;
        bb[dt] = *reinterpret_cast<const short8*>(eks + d * SN + (n0 ^ ((d & 7) << 3)));
      }
#pragma unroll
      for (int am = 0; am < 2; ++am)
#pragma unroll
        for (int dt = 0; dt < 4; ++dt)
          acc[am][dt] = __builtin_amdgcn_mfma_f32_16x16x32_bf16(a[am], bb[dt], acc[am][dt], 0, 0, 0);
    }
    asm volatile("s_waitcnt lgkmcnt(0)" ::: "memory");
    __builtin_amdgcn_s_barrier();
    __builtin_amdgcn_sched_barrier(0);
  }

  // ---- epilogue: part + zpart (deterministic, no atomics) ----
  float* P = part + ((size_t)kc * B_ + b) * C_ * C_;
#pragma unroll
  for (int am = 0; am < 2; ++am)
#pragma unroll
    for (int dt = 0; dt < 4; ++dt)
#pragma unroll
      for (int r = 0; r < 4; ++r) {
        const int c = cg * 32 + am * 16 + lg * 4 + r;
        const int d = dh * 64 + dt * 16 + li;
        P[c * C_ + d] = acc[am][dt][r];
      }
  if (mat == 0) {
#pragma unroll
    for (int dt = 0; dt < 2; ++dt) {
      float z = zac[dt];
      z += __shfl_xor(z, 16);
      z += __shfl_xor(z, 32);
      if (lg == 0)
        zpart[((size_t)kc * B_ + b) * C_ + dblk * 32 + dt * 16 + li] = z;
    }
  }
}

// ---------------------------------------------------------------------------
// KB2: cs = (sum_kc part)/Z ; M = cs·qw (bf16), T = cs·qb
// (unchanged from rounds 8-13)
// ---------------------------------------------------------------------------
__global__ __launch_bounds__(256) void kb2_fin(
    const float* __restrict__ part, const float* __restrict__ zpart,
    const float* __restrict__ qw, const float* __restrict__ qb,
    u16* __restrict__ M, float* __restrict__ T) {
  const int b = blockIdx.y;
  const int cs0 = blockIdx.x * 16;
  const int tid = threadIdx.x;
  __shared__ float cs[16][128];
  __shared__ float Zs[128];
  if (tid < 128) {
    float s = 0.f;
    for (int kc = 0; kc < NC; ++kc)
      s += zpart[((size_t)kc * B_ + b) * C_ + tid];
    Zs[tid] = s;
  }
  __syncthreads();
#pragma unroll
  for (int i = 0; i < 8; ++i) {
    const int e = tid + i * 256;
    const int cl = e >> 7, d = e & 127;
    float s = 0.f;
    for (int kc = 0; kc < NC; ++kc)
      s += part[(((size_t)kc * B_ + b) * C_ + (cs0 + cl)) * C_ + d];
    cs[cl][d] = s / Zs[d];
  }
  __syncthreads();
  const int cl = tid >> 4, e0 = (tid & 15) * 8;
  float m[8] = {};
  for (int d = 0; d < 128; ++d) {
    const float cv = cs[cl][d];
    const float* qr = qw + d * C_ + e0;
#pragma unroll
    for (int j = 0; j < 8; ++j) m[j] += cv * qr[j];
  }
  u16* mp = M + ((size_t)b * C_ + cs0 + cl) * C_ + e0;
#pragma unroll
  for (int j = 0; j < 8; ++j) mp[j] = (u16)f2bf(m[j]);
  if (tid < 16) {
    float tv = 0.f;
    for (int d = 0; d < 128; ++d) tv += cs[tid][d] * qb[d];
    T[b * C_ + cs0 + tid] = tv;
  }
}

// ---------------------------------------------------------------------------
// K4: out = M·q_feat + T (fp32).  grid (32, B) remapped, 512 thr = 8 waves.
// Round-12 structure (which measured 41.5 µs) with ONE change: all 4
// subtiles' accumulators are HELD IN REGISTERS (acc[4][8] f32x4, statically
// indexed under full unroll) and stores are removed from the loop — the
// loop is now a pure read+MFMA stream (KA's regime, ~4 TB/s) and the
// block's whole 256 KB output is written as a single epilogue burst
// (fillBuffer's regime, ~6.8 TB/s).  Tests the read/write-interleave
// theory of the 41-µs invariance.  Same products, same store values.
// ---------------------------------------------------------------------------
#define K4_LOADS(ST_) do {                                                   \
  _Pragma("unroll") for (int h_ = 0; h_ < 2; ++h_)                           \
  _Pragma("unroll") for (int j_ = 0; j_ < 16; ++j_)                          \
    xr[h_][j_] = qw_[(size_t)j_ * N_ + (ST_) * SN + h_ * 64 + lane];         \
} while (0)

#define K4_XWRITE(BUF_) do {                                                 \
  _Pragma("unroll") for (int h_ = 0; h_ < 2; ++h_) {                         \
    const int n_ = h_ * 64 + lane;                                           \
    unsigned pk_[8];                                                         \
    _Pragma("unroll") for (int p_ = 0; p_ < 8; ++p_)                         \
      pk_[p_] = cvtpk(xr[h_][2 * p_], xr[h_][2 * p_ + 1]);                   \
    _Pragma("unroll") for (int o_ = 0; o_ < 2; ++o_) {                       \
      uint4 q_;                                                              \
      q_.x = pk_[o_ * 4]; q_.y = pk_[o_ * 4 + 1];                            \
      q_.z = pk_[o_ * 4 + 2]; q_.w = pk_[o_ * 4 + 3];                        \
      *reinterpret_cast<uint4*>(                                             \
          (BUF_) + n_ * SN + ((w * 16 + o_ * 8) ^ ((n_ & 7) << 3))) = q_;    \
    }                                                                        \
  }                                                                          \
} while (0)

__global__ __launch_bounds__(512) void k4_out(const u16* __restrict__ M,
                                              const float* __restrict__ T,
                                              const float* __restrict__ q,
                                              float* __restrict__ out) {
  __shared__ u16 qt[2][SN * C_];  // double-buffered [n][d] bf16, 2 x 32 KB

  const int fid = blockIdx.x + blockIdx.y * NC;
  const int fid2 = (fid & 7) * 32 + (fid >> 3);  // XCD k -> batch k
  const int b = fid2 >> 5, kc = fid2 & 31;
  const int nb = kc * CHN;
  const int tid = threadIdx.x;
  const int w = tid >> 6, lane = tid & 63;
  const int lg = lane >> 4, li = lane & 15;

  const float* qw_ = q + (size_t)b * C_ * N_ + nb + (size_t)(w * 16) * N_;

  // M fragments (A operand rows c = w*16+li) + T (rows c = w*16+lg*4+r)
  short8 mreg[4];
  const u16* Mb = M + (size_t)b * C_ * C_;
#pragma unroll
  for (int ks = 0; ks < 4; ++ks)
    mreg[ks] = *reinterpret_cast<const short8*>(
        Mb + (w * 16 + li) * C_ + ks * 32 + lg * 8);
  float tcv[4];
#pragma unroll
  for (int r = 0; r < 4; ++r) tcv[r] = T[b * C_ + w * 16 + lg * 4 + r];

  float xr[2][16];        // reg-staged q: [n-half][d-row j]
  f32x4 acc[NST][8] = {}; // held accumulators: [subtile][nt] = 128 VGPR

  K4_LOADS(0);
  K4_XWRITE(&qt[0][0]);
  K4_LOADS(1);
  asm volatile("s_waitcnt lgkmcnt(0)" ::: "memory");
  __builtin_amdgcn_s_barrier();
  __builtin_amdgcn_sched_barrier(0);

#pragma unroll
  for (int st = 0; st < NST; ++st) {
    const u16* xc = &qt[st & 1][0];

    if (st < NST - 1) {
      K4_XWRITE(&qt[(st + 1) & 1][0]);
      if (st < NST - 2) K4_LOADS(st + 2);
    }

    // ---- MFMA: D[c][n]; wave w owns c in [w*16,+16), n in [0,128) ----
#pragma unroll
    for (int nt = 0; nt < 8; ++nt) {
      const int n = nt * 16 + li;
#pragma unroll
      for (int ks = 0; ks < 4; ++ks) {
        short8 bb = *reinterpret_cast<const short8*>(
            xc + n * SN + ((ks * 32 + lg * 8) ^ ((n & 7) << 3)));
        acc[st][nt] = __builtin_amdgcn_mfma_f32_16x16x32_bf16(
            mreg[ks], bb, acc[st][nt], 0, 0, 0);
      }
    }

    asm volatile("s_waitcnt lgkmcnt(0)" ::: "memory");
    __builtin_amdgcn_s_barrier();
    __builtin_amdgcn_sched_barrier(0);
  }

  // ---- epilogue: single pure-write burst of the block's 256 KB ----
#pragma unroll
  for (int r = 0; r < 4; ++r) {
    const int c = w * 16 + lg * 4 + r;
    float* op = out + ((size_t)b * C_ + c) * N_ + nb;
    const float t = tcv[r];
#pragma unroll
    for (int st = 0; st < NST; ++st)
#pragma unroll
      for (int nt = 0; nt < 8; ++nt)
        op[st * SN + nt * 16 + li] = acc[st][nt][r] + t;
  }
}

// ---------------------------------------------------------------------------
extern "C" void kernel_launch(void* const* d_in, const int* in_sizes, int n_in,
                              void* d_out, int out_size, void* d_ws, size_t ws_size,
                              hipStream_t stream) {
  const float* q_feat  = (const float*)d_in[0];
  const float* kv_feat = (const float*)d_in[1];
  const float* q_w = (const float*)d_in[2];
  const float* q_b = (const float*)d_in[3];
  const float* k_w = (const float*)d_in[4];
  const float* k_b = (const float*)d_in[5];
  const float* v_w = (const float*)d_in[6];
  const float* v_b = (const float*)d_in[7];
  float* out = (float*)d_out;

  char* ws = (char*)d_ws;
  const size_t szPart = (size_t)NC * B_ * C_ * C_ * sizeof(float);  // 16 MB
  const size_t szZp   = (size_t)NC * B_ * C_ * sizeof(float);       // 128 KB
  const size_t szWbf  = (size_t)2 * C_ * C_ * sizeof(u16);          // 64 KB
  const size_t szM    = (size_t)B_ * C_ * C_ * sizeof(u16);         // 256 KB

  float* part  = (float*)ws;
  float* zpart = (float*)(ws + szPart);
  u16*   wbf   = (u16*)(ws + szPart + szZp);
  u16*   M     = (u16*)(ws + szPart + szZp + szWbf);
  float* T     = (float*)(ws + szPart + szZp + szWbf + szM);

  k0_wcvt<<<dim3(32), 256, 0, stream>>>(k_w, v_w, wbf);
  ka_projctx<<<dim3(NC, B_), 512, 0, stream>>>(kv_feat, wbf, k_b, v_b, part, zpart);
  kb2_fin<<<dim3(8, B_), 256, 0, stream>>>(part, zpart, q_w, q_b, M, T);
  k4_out<<<dim3(NC, B_), 512, 0, stream>>>(M, T, q_feat, out);
}

// Round 15
// 74.393 us; speedup vs baseline: 1.1793x; 1.0279x over previous
//
#include <hip/hip_runtime.h>
#include <hip/hip_bf16.h>
#include <cstdint>

#define B_ 8
#define C_ 128
#define N_ 16384   // H*W
#define CHN 512    // n per block (KA and K4)
#define SN 128     // n per subtile
#define NST 4      // subtiles per block
#define NC (N_ / CHN)  // 32 chunks

typedef __attribute__((ext_vector_type(8))) short short8;
typedef __attribute__((ext_vector_type(4))) float f32x4;
typedef __attribute__((ext_vector_type(4))) unsigned short us4;
typedef unsigned short u16;

__device__ __forceinline__ short f2bf(float f) {
  union { float f; unsigned u; } c; c.f = f;
  unsigned r = (c.u + 0x7FFFu + ((c.u >> 16) & 1u)) >> 16;
  return (short)r;
}

__device__ __forceinline__ unsigned cvtpk(float lo, float hi) {
  unsigned r;
  asm("v_cvt_pk_bf16_f32 %0, %1, %2" : "=v"(r) : "v"(lo), "v"(hi));
  return r;
}

union SB { short8 s8; unsigned u[4]; };

// ---------------------------------------------------------------------------
// K0: preconvert k_w, v_w (fp32) -> wbf (bf16 [2][128][128])
// ---------------------------------------------------------------------------
__global__ __launch_bounds__(256) void k0_wcvt(const float* __restrict__ kw,
                                               const float* __restrict__ vw,
                                               u16* __restrict__ wbf) {
  const int g = blockIdx.x * 256 + threadIdx.x;  // 0..8191 float4s
  const int mat = g >> 12, o4 = g & 4095;
  const float* src = mat ? vw : kw;
  float4 f = reinterpret_cast<const float4*>(src)[o4];
  us4 s;
  s[0] = (u16)f2bf(f.x); s[1] = (u16)f2bf(f.y);
  s[2] = (u16)f2bf(f.z); s[3] = (u16)f2bf(f.w);
  reinterpret_cast<us4*>(wbf + (size_t)mat * C_ * C_)[o4] = s;
}

// ---------------------------------------------------------------------------
// Staging v2 (VECTORIZED): lane loads float4 (n-quad) of d-row
// (lane>>5)*8 + i; per instruction 2 rows x 512 B contiguous (was 4B/lane
// scalar dwords -> 4x the in-flight read bytes per wave).  cvtpk pairs run
// ALONG d across the 8 regs, so each uint4 LDS write carries the same
// d-octet-for-fixed-n bytes as rounds 6-14 — tile layout, swizzle, and all
// MFMA-side reads are bit-identical.
// ---------------------------------------------------------------------------
#define STAGE_LOADS(BASE_, ST_) do {                                         \
  _Pragma("unroll") for (int i_ = 0; i_ < 8; ++i_)                           \
    xf[i_] = *reinterpret_cast<const f32x4*>(                                \
        (BASE_) + (size_t)((lane >> 5) * 8 + i_) * N_ + (ST_) * SN +         \
        (lane & 31) * 4);                                                    \
} while (0)

#define STAGE_XWRITE(BUF_) do {                                              \
  const int db_ = w * 16 + (lane >> 5) * 8;                                  \
  _Pragma("unroll") for (int k_ = 0; k_ < 4; ++k_) {                         \
    const int n_ = (lane & 31) * 4 + k_;                                     \
    uint4 q_;                                                                \
    q_.x = cvtpk(xf[0][k_], xf[1][k_]);                                      \
    q_.y = cvtpk(xf[2][k_], xf[3][k_]);                                      \
    q_.z = cvtpk(xf[4][k_], xf[5][k_]);                                      \
    q_.w = cvtpk(xf[6][k_], xf[7][k_]);                                      \
    *reinterpret_cast<uint4*>(                                               \
        (BUF_) + n_ * SN + (db_ ^ ((n_ & 7) << 3))) = q_;                    \
  }                                                                          \
} while (0)

// ---------------------------------------------------------------------------
// KA: fused projection + context partial (rounds 6-14 core, passed 0.03125)
// with chunked XCD remap; staging loads vectorized (v2).
// ---------------------------------------------------------------------------
__global__ __launch_bounds__(512, 2) void ka_projctx(
    const float* __restrict__ kv, const u16* __restrict__ wbf,
    const float* __restrict__ kb, const float* __restrict__ vb,
    float* __restrict__ part, float* __restrict__ zpart) {
  __shared__ u16 xt[2][C_ * SN];   // 2 x 32 KB transposed bf16 x
  __shared__ u16 eks[C_ * SN];     // 32 KB EK stash [d][n]
  __shared__ u16 vs [C_ * SN];     // 32 KB V  stash [c][n]

  const int fid = blockIdx.x + blockIdx.y * NC;
  const int fid2 = (fid & 7) * 32 + (fid >> 3);  // XCD k -> batch k
  const int b = fid2 >> 5, kc = fid2 & 31;
  const int tid = threadIdx.x;
  const int w = tid >> 6, lane = tid & 63;
  const int lg = lane >> 4, li = lane & 15;
  const int mat = w >> 2, dblk = w & 3;
  const int cg = w >> 1, dh = w & 1;

  const float* xb = kv + (size_t)b * C_ * N_ + (size_t)kc * CHN;
  const float* xw = xb + (size_t)(w * 16) * N_;  // wave's 16 c-rows
  const u16* Wm = wbf + (size_t)mat * C_ * C_;
  const float* biasp = mat ? vb : kb;
  u16* S = mat ? vs : eks;

  short8 wreg[2][4];
#pragma unroll
  for (int dt = 0; dt < 2; ++dt)
#pragma unroll
    for (int ks = 0; ks < 4; ++ks)
      wreg[dt][ks] = *reinterpret_cast<const short8*>(
          Wm + (dblk * 32 + dt * 16 + li) * C_ + ks * 32 + lg * 8);
  float bias2[2];
#pragma unroll
  for (int dt = 0; dt < 2; ++dt) bias2[dt] = biasp[dblk * 32 + dt * 16 + li];

  f32x4 acc[2][4] = {};   // ctx accumulator [am c][dt d]
  float zac[2] = {0.f, 0.f};
  f32x4 xf[8];            // reg-staged x: 8 d-rows x 4 n

  STAGE_LOADS(xw, 0);
  STAGE_XWRITE(&xt[0][0]);
  STAGE_LOADS(xw, 1);
  asm volatile("s_waitcnt lgkmcnt(0)" ::: "memory");
  __builtin_amdgcn_s_barrier();
  __builtin_amdgcn_sched_barrier(0);

#pragma unroll
  for (int st = 0; st < NST; ++st) {
    const u16* xc = &xt[st & 1][0];

    if (st < NST - 1) {
      STAGE_XWRITE(&xt[(st + 1) & 1][0]);
      if (st < NST - 2) STAGE_LOADS(xw, st + 2);
    }

    // ---- proj: D[n][d] = xT · W^T, in nt-pairs ----
#pragma unroll
    for (int h2 = 0; h2 < 4; ++h2) {
      f32x4 pacc[2][2] = {};  // [ntl][dt]
#pragma unroll
      for (int ntl = 0; ntl < 2; ++ntl) {
        const int n = (h2 * 2 + ntl) * 16 + li;
#pragma unroll
        for (int ks = 0; ks < 4; ++ks) {
          short8 a = *reinterpret_cast<const short8*>(
              xc + n * SN + ((ks * 32 + lg * 8) ^ ((n & 7) << 3)));
#pragma unroll
          for (int dt = 0; dt < 2; ++dt)
            pacc[ntl][dt] = __builtin_amdgcn_mfma_f32_16x16x32_bf16(
                a, wreg[dt][ks], pacc[ntl][dt], 0, 0, 0);
        }
      }
#pragma unroll
      for (int dt = 0; dt < 2; ++dt) {
        const int d = dblk * 32 + dt * 16 + li;
        const float bias = bias2[dt];
#pragma unroll
        for (int ntl = 0; ntl < 2; ++ntl) {
          float v0 = pacc[ntl][dt][0] + bias;
          float v1 = pacc[ntl][dt][1] + bias;
          float v2 = pacc[ntl][dt][2] + bias;
          float v3 = pacc[ntl][dt][3] + bias;
          if (mat == 0) {
            v0 = __expf(v0); v1 = __expf(v1); v2 = __expf(v2); v3 = __expf(v3);
            zac[dt] += (v0 + v1) + (v2 + v3);
          }
          const int nq = (h2 * 2 + ntl) * 16 + lg * 4;
          uint2 pk; pk.x = cvtpk(v0, v1); pk.y = cvtpk(v2, v3);
          *reinterpret_cast<uint2*>(S + d * SN + (nq ^ ((d & 7) << 3))) = pk;
        }
      }
    }
    asm volatile("s_waitcnt lgkmcnt(0)" ::: "memory");
    __builtin_amdgcn_s_barrier();
    __builtin_amdgcn_sched_barrier(0);

    // ---- ctx: part += V·EK^T over this subtile's 128 n ----
#pragma unroll
    for (int kk = 0; kk < 4; ++kk) {
      const int n0 = kk * 32 + lg * 8;
      short8 a[2], bb[4];
#pragma unroll
      for (int am = 0; am < 2; ++am) {
        const int c = cg * 32 + am * 16 + li;
        a[am] = *reinterpret_cast<const short8*>(vs + c * SN + (n0 ^ ((c & 7) << 3)));
      }
#pragma unroll
      for (int dt = 0; dt < 4; ++dt) {
        const int d = dh * 64 + dt * 16 + li;
        bb[dt] = *reinterpret_cast<const short8*>(eks + d * SN + (n0 ^ ((d & 7) << 3)));
      }
#pragma unroll
      for (int am = 0; am < 2; ++am)
#pragma unroll
        for (int dt = 0; dt < 4; ++dt)
          acc[am][dt] = __builtin_amdgcn_mfma_f32_16x16x32_bf16(a[am], bb[dt], acc[am][dt], 0, 0, 0);
    }
    asm volatile("s_waitcnt lgkmcnt(0)" ::: "memory");
    __builtin_amdgcn_s_barrier();
    __builtin_amdgcn_sched_barrier(0);
  }

  // ---- epilogue: part + zpart (deterministic, no atomics) ----
  float* P = part + ((size_t)kc * B_ + b) * C_ * C_;
#pragma unroll
  for (int am = 0; am < 2; ++am)
#pragma unroll
    for (int dt = 0; dt < 4; ++dt)
#pragma unroll
      for (int r = 0; r < 4; ++r) {
        const int c = cg * 32 + am * 16 + lg * 4 + r;
        const int d = dh * 64 + dt * 16 + li;
        P[c * C_ + d] = acc[am][dt][r];
      }
  if (mat == 0) {
#pragma unroll
    for (int dt = 0; dt < 2; ++dt) {
      float z = zac[dt];
      z += __shfl_xor(z, 16);
      z += __shfl_xor(z, 32);
      if (lg == 0)
        zpart[((size_t)kc * B_ + b) * C_ + dblk * 32 + dt * 16 + li] = z;
    }
  }
}

// ---------------------------------------------------------------------------
// KB2: cs = (sum_kc part)/Z ; M = cs·qw (bf16), T = cs·qb
// (unchanged from rounds 8-14)
// ---------------------------------------------------------------------------
__global__ __launch_bounds__(256) void kb2_fin(
    const float* __restrict__ part, const float* __restrict__ zpart,
    const float* __restrict__ qw, const float* __restrict__ qb,
    u16* __restrict__ M, float* __restrict__ T) {
  const int b = blockIdx.y;
  const int cs0 = blockIdx.x * 16;
  const int tid = threadIdx.x;
  __shared__ float cs[16][128];
  __shared__ float Zs[128];
  if (tid < 128) {
    float s = 0.f;
    for (int kc = 0; kc < NC; ++kc)
      s += zpart[((size_t)kc * B_ + b) * C_ + tid];
    Zs[tid] = s;
  }
  __syncthreads();
#pragma unroll
  for (int i = 0; i < 8; ++i) {
    const int e = tid + i * 256;
    const int cl = e >> 7, d = e & 127;
    float s = 0.f;
    for (int kc = 0; kc < NC; ++kc)
      s += part[(((size_t)kc * B_ + b) * C_ + (cs0 + cl)) * C_ + d];
    cs[cl][d] = s / Zs[d];
  }
  __syncthreads();
  const int cl = tid >> 4, e0 = (tid & 15) * 8;
  float m[8] = {};
  for (int d = 0; d < 128; ++d) {
    const float cv = cs[cl][d];
    const float* qr = qw + d * C_ + e0;
#pragma unroll
    for (int j = 0; j < 8; ++j) m[j] += cv * qr[j];
  }
  u16* mp = M + ((size_t)b * C_ + cs0 + cl) * C_ + e0;
#pragma unroll
  for (int j = 0; j < 8; ++j) mp[j] = (u16)f2bf(m[j]);
  if (tid < 16) {
    float tv = 0.f;
    for (int d = 0; d < 128; ++d) tv += cs[tid][d] * qb[d];
    T[b * C_ + cs0 + tid] = tv;
  }
}

// ---------------------------------------------------------------------------
// K4: out = M·q_feat + T (fp32).  grid (32, B) remapped, 512 thr = 8 waves.
// Round-14 structure (reg-held accumulators, deferred epilogue write burst)
// with staging loads vectorized (v2).  Same products, same store values.
// ---------------------------------------------------------------------------
__global__ __launch_bounds__(512) void k4_out(const u16* __restrict__ M,
                                              const float* __restrict__ T,
                                              const float* __restrict__ q,
                                              float* __restrict__ out) {
  __shared__ u16 qt[2][SN * C_];  // double-buffered [n][d] bf16, 2 x 32 KB

  const int fid = blockIdx.x + blockIdx.y * NC;
  const int fid2 = (fid & 7) * 32 + (fid >> 3);  // XCD k -> batch k
  const int b = fid2 >> 5, kc = fid2 & 31;
  const int nb = kc * CHN;
  const int tid = threadIdx.x;
  const int w = tid >> 6, lane = tid & 63;
  const int lg = lane >> 4, li = lane & 15;

  const float* qw_ = q + (size_t)b * C_ * N_ + nb + (size_t)(w * 16) * N_;

  // M fragments (A operand rows c = w*16+li) + T (rows c = w*16+lg*4+r)
  short8 mreg[4];
  const u16* Mb = M + (size_t)b * C_ * C_;
#pragma unroll
  for (int ks = 0; ks < 4; ++ks)
    mreg[ks] = *reinterpret_cast<const short8*>(
        Mb + (w * 16 + li) * C_ + ks * 32 + lg * 8);
  float tcv[4];
#pragma unroll
  for (int r = 0; r < 4; ++r) tcv[r] = T[b * C_ + w * 16 + lg * 4 + r];

  f32x4 xf[8];            // reg-staged q: 8 d-rows x 4 n
  f32x4 acc[NST][8] = {}; // held accumulators: [subtile][nt] = 128 VGPR

  STAGE_LOADS(qw_, 0);
  STAGE_XWRITE(&qt[0][0]);
  STAGE_LOADS(qw_, 1);
  asm volatile("s_waitcnt lgkmcnt(0)" ::: "memory");
  __builtin_amdgcn_s_barrier();
  __builtin_amdgcn_sched_barrier(0);

#pragma unroll
  for (int st = 0; st < NST; ++st) {
    const u16* xc = &qt[st & 1][0];

    if (st < NST - 1) {
      STAGE_XWRITE(&qt[(st + 1) & 1][0]);
      if (st < NST - 2) STAGE_LOADS(qw_, st + 2);
    }

    // ---- MFMA: D[c][n]; wave w owns c in [w*16,+16), n in [0,128) ----
#pragma unroll
    for (int nt = 0; nt < 8; ++nt) {
      const int n = nt * 16 + li;
#pragma unroll
      for (int ks = 0; ks < 4; ++ks) {
        short8 bb = *reinterpret_cast<const short8*>(
            xc + n * SN + ((ks * 32 + lg * 8) ^ ((n & 7) << 3)));
        acc[st][nt] = __builtin_amdgcn_mfma_f32_16x16x32_bf16(
            mreg[ks], bb, acc[st][nt], 0, 0, 0);
      }
    }

    asm volatile("s_waitcnt lgkmcnt(0)" ::: "memory");
    __builtin_amdgcn_s_barrier();
    __builtin_amdgcn_sched_barrier(0);
  }

  // ---- epilogue: single pure-write burst of the block's 256 KB ----
#pragma unroll
  for (int r = 0; r < 4; ++r) {
    const int c = w * 16 + lg * 4 + r;
    float* op = out + ((size_t)b * C_ + c) * N_ + nb;
    const float t = tcv[r];
#pragma unroll
    for (int st = 0; st < NST; ++st)
#pragma unroll
      for (int nt = 0; nt < 8; ++nt)
        op[st * SN + nt * 16 + li] = acc[st][nt][r] + t;
  }
}

// ---------------------------------------------------------------------------
extern "C" void kernel_launch(void* const* d_in, const int* in_sizes, int n_in,
                              void* d_out, int out_size, void* d_ws, size_t ws_size,
                              hipStream_t stream) {
  const float* q_feat  = (const float*)d_in[0];
  const float* kv_feat = (const float*)d_in[1];
  const float* q_w = (const float*)d_in[2];
  const float* q_b = (const float*)d_in[3];
  const float* k_w = (const float*)d_in[4];
  const float* k_b = (const float*)d_in[5];
  const float* v_w = (const float*)d_in[6];
  const float* v_b = (const float*)d_in[7];
  float* out = (float*)d_out;

  char* ws = (char*)d_ws;
  const size_t szPart = (size_t)NC * B_ * C_ * C_ * sizeof(float);  // 16 MB
  const size_t szZp   = (size_t)NC * B_ * C_ * sizeof(float);       // 128 KB
  const size_t szWbf  = (size_t)2 * C_ * C_ * sizeof(u16);          // 64 KB
  const size_t szM    = (size_t)B_ * C_ * C_ * sizeof(u16);         // 256 KB

  float* part  = (float*)ws;
  float* zpart = (float*)(ws + szPart);
  u16*   wbf   = (u16*)(ws + szPart + szZp);
  u16*   M     = (u16*)(ws + szPart + szZp + szWbf);
  float* T     = (float*)(ws + szPart + szZp + szWbf + szM);

  k0_wcvt<<<dim3(32), 256, 0, stream>>>(k_w, v_w, wbf);
  ka_projctx<<<dim3(NC, B_), 512, 0, stream>>>(kv_feat, wbf, k_b, v_b, part, zpart);
  kb2_fin<<<dim3(8, B_), 256, 0, stream>>>(part, zpart, q_w, q_b, M, T);
  k4_out<<<dim3(NC, B_), 512, 0, stream>>>(M, T, q_feat, out);
}

// Round 16
// 72.891 us; speedup vs baseline: 1.2036x; 1.0206x over previous
//
#include <hip/hip_runtime.h>
#include <hip/hip_bf16.h>
#include <cstdint>

#define B_ 8
#define C_ 128
#define N_ 16384   // H*W
#define CHN 512    // n per KA block
#define SN 128     // n per subtile
#define NST 4      // subtiles per KA block
#define NC (N_ / CHN)  // 32 chunks

typedef __attribute__((ext_vector_type(8))) short short8;
typedef __attribute__((ext_vector_type(4))) float f32x4;
typedef __attribute__((ext_vector_type(4))) unsigned short us4;
typedef unsigned short u16;

__device__ __forceinline__ short f2bf(float f) {
  union { float f; unsigned u; } c; c.f = f;
  unsigned r = (c.u + 0x7FFFu + ((c.u >> 16) & 1u)) >> 16;
  return (short)r;
}

__device__ __forceinline__ unsigned cvtpk(float lo, float hi) {
  unsigned r;
  asm("v_cvt_pk_bf16_f32 %0, %1, %2" : "=v"(r) : "v"(lo), "v"(hi));
  return r;
}

union SB { short8 s8; unsigned u[4]; };

// ---------------------------------------------------------------------------
// K0: preconvert k_w, v_w (fp32) -> wbf (bf16 [2][128][128])
// ---------------------------------------------------------------------------
__global__ __launch_bounds__(256) void k0_wcvt(const float* __restrict__ kw,
                                               const float* __restrict__ vw,
                                               u16* __restrict__ wbf) {
  const int g = blockIdx.x * 256 + threadIdx.x;  // 0..8191 float4s
  const int mat = g >> 12, o4 = g & 4095;
  const float* src = mat ? vw : kw;
  float4 f = reinterpret_cast<const float4*>(src)[o4];
  us4 s;
  s[0] = (u16)f2bf(f.x); s[1] = (u16)f2bf(f.y);
  s[2] = (u16)f2bf(f.z); s[3] = (u16)f2bf(f.w);
  reinterpret_cast<us4*>(wbf + (size_t)mat * C_ * C_)[o4] = s;
}

// ---------------------------------------------------------------------------
// Staging (vectorized, r15 form): lane loads float4 (n-quad) of d-row
// (lane>>5)*8 + i; cvtpk pairs along d so each uint4 LDS write carries a
// d-octet for fixed n — tile layout identical to rounds 6-15.
// ---------------------------------------------------------------------------
#define STAGE_LOADS(BASE_, ST_) do {                                         \
  _Pragma("unroll") for (int i_ = 0; i_ < 8; ++i_)                           \
    xf[i_] = *reinterpret_cast<const f32x4*>(                                \
        (BASE_) + (size_t)((lane >> 5) * 8 + i_) * N_ + (ST_) * SN +         \
        (lane & 31) * 4);                                                    \
} while (0)

#define STAGE_XWRITE(BUF_) do {                                              \
  const int db_ = w * 16 + (lane >> 5) * 8;                                  \
  _Pragma("unroll") for (int k_ = 0; k_ < 4; ++k_) {                         \
    const int n_ = (lane & 31) * 4 + k_;                                     \
    uint4 q_;                                                                \
    q_.x = cvtpk(xf[0][k_], xf[1][k_]);                                      \
    q_.y = cvtpk(xf[2][k_], xf[3][k_]);                                      \
    q_.z = cvtpk(xf[4][k_], xf[5][k_]);                                      \
    q_.w = cvtpk(xf[6][k_], xf[7][k_]);                                      \
    *reinterpret_cast<uint4*>(                                               \
        (BUF_) + n_ * SN + (db_ ^ ((n_ & 7) << 3))) = q_;                    \
  }                                                                          \
} while (0)

// ---------------------------------------------------------------------------
// KA: fused projection + context partial (rounds 6-15 core, passed 0.03125)
// with chunked XCD remap; staging loads vectorized.  Unchanged from r15.
// ---------------------------------------------------------------------------
__global__ __launch_bounds__(512, 2) void ka_projctx(
    const float* __restrict__ kv, const u16* __restrict__ wbf,
    const float* __restrict__ kb, const float* __restrict__ vb,
    float* __restrict__ part, float* __restrict__ zpart) {
  __shared__ u16 xt[2][C_ * SN];   // 2 x 32 KB transposed bf16 x
  __shared__ u16 eks[C_ * SN];     // 32 KB EK stash [d][n]
  __shared__ u16 vs [C_ * SN];     // 32 KB V  stash [c][n]

  const int fid = blockIdx.x + blockIdx.y * NC;
  const int fid2 = (fid & 7) * 32 + (fid >> 3);  // XCD k -> batch k
  const int b = fid2 >> 5, kc = fid2 & 31;
  const int tid = threadIdx.x;
  const int w = tid >> 6, lane = tid & 63;
  const int lg = lane >> 4, li = lane & 15;
  const int mat = w >> 2, dblk = w & 3;
  const int cg = w >> 1, dh = w & 1;

  const float* xb = kv + (size_t)b * C_ * N_ + (size_t)kc * CHN;
  const float* xw = xb + (size_t)(w * 16) * N_;  // wave's 16 c-rows
  const u16* Wm = wbf + (size_t)mat * C_ * C_;
  const float* biasp = mat ? vb : kb;
  u16* S = mat ? vs : eks;

  short8 wreg[2][4];
#pragma unroll
  for (int dt = 0; dt < 2; ++dt)
#pragma unroll
    for (int ks = 0; ks < 4; ++ks)
      wreg[dt][ks] = *reinterpret_cast<const short8*>(
          Wm + (dblk * 32 + dt * 16 + li) * C_ + ks * 32 + lg * 8);
  float bias2[2];
#pragma unroll
  for (int dt = 0; dt < 2; ++dt) bias2[dt] = biasp[dblk * 32 + dt * 16 + li];

  f32x4 acc[2][4] = {};   // ctx accumulator [am c][dt d]
  float zac[2] = {0.f, 0.f};
  f32x4 xf[8];            // reg-staged x: 8 d-rows x 4 n

  STAGE_LOADS(xw, 0);
  STAGE_XWRITE(&xt[0][0]);
  STAGE_LOADS(xw, 1);
  asm volatile("s_waitcnt lgkmcnt(0)" ::: "memory");
  __builtin_amdgcn_s_barrier();
  __builtin_amdgcn_sched_barrier(0);

#pragma unroll
  for (int st = 0; st < NST; ++st) {
    const u16* xc = &xt[st & 1][0];

    if (st < NST - 1) {
      STAGE_XWRITE(&xt[(st + 1) & 1][0]);
      if (st < NST - 2) STAGE_LOADS(xw, st + 2);
    }

    // ---- proj: D[n][d] = xT · W^T, in nt-pairs ----
#pragma unroll
    for (int h2 = 0; h2 < 4; ++h2) {
      f32x4 pacc[2][2] = {};  // [ntl][dt]
#pragma unroll
      for (int ntl = 0; ntl < 2; ++ntl) {
        const int n = (h2 * 2 + ntl) * 16 + li;
#pragma unroll
        for (int ks = 0; ks < 4; ++ks) {
          short8 a = *reinterpret_cast<const short8*>(
              xc + n * SN + ((ks * 32 + lg * 8) ^ ((n & 7) << 3)));
#pragma unroll
          for (int dt = 0; dt < 2; ++dt)
            pacc[ntl][dt] = __builtin_amdgcn_mfma_f32_16x16x32_bf16(
                a, wreg[dt][ks], pacc[ntl][dt], 0, 0, 0);
        }
      }
#pragma unroll
      for (int dt = 0; dt < 2; ++dt) {
        const int d = dblk * 32 + dt * 16 + li;
        const float bias = bias2[dt];
#pragma unroll
        for (int ntl = 0; ntl < 2; ++ntl) {
          float v0 = pacc[ntl][dt][0] + bias;
          float v1 = pacc[ntl][dt][1] + bias;
          float v2 = pacc[ntl][dt][2] + bias;
          float v3 = pacc[ntl][dt][3] + bias;
          if (mat == 0) {
            v0 = __expf(v0); v1 = __expf(v1); v2 = __expf(v2); v3 = __expf(v3);
            zac[dt] += (v0 + v1) + (v2 + v3);
          }
          const int nq = (h2 * 2 + ntl) * 16 + lg * 4;
          uint2 pk; pk.x = cvtpk(v0, v1); pk.y = cvtpk(v2, v3);
          *reinterpret_cast<uint2*>(S + d * SN + (nq ^ ((d & 7) << 3))) = pk;
        }
      }
    }
    asm volatile("s_waitcnt lgkmcnt(0)" ::: "memory");
    __builtin_amdgcn_s_barrier();
    __builtin_amdgcn_sched_barrier(0);

    // ---- ctx: part += V·EK^T over this subtile's 128 n ----
#pragma unroll
    for (int kk = 0; kk < 4; ++kk) {
      const int n0 = kk * 32 + lg * 8;
      short8 a[2], bb[4];
#pragma unroll
      for (int am = 0; am < 2; ++am) {
        const int c = cg * 32 + am * 16 + li;
        a[am] = *reinterpret_cast<const short8*>(vs + c * SN + (n0 ^ ((c & 7) << 3)));
      }
#pragma unroll
      for (int dt = 0; dt < 4; ++dt) {
        const int d = dh * 64 + dt * 16 + li;
        bb[dt] = *reinterpret_cast<const short8*>(eks + d * SN + (n0 ^ ((d & 7) << 3)));
      }
#pragma unroll
      for (int am = 0; am < 2; ++am)
#pragma unroll
        for (int dt = 0; dt < 4; ++dt)
          acc[am][dt] = __builtin_amdgcn_mfma_f32_16x16x32_bf16(a[am], bb[dt], acc[am][dt], 0, 0, 0);
    }
    asm volatile("s_waitcnt lgkmcnt(0)" ::: "memory");
    __builtin_amdgcn_s_barrier();
    __builtin_amdgcn_sched_barrier(0);
  }

  // ---- epilogue: part + zpart (deterministic, no atomics) ----
  float* P = part + ((size_t)kc * B_ + b) * C_ * C_;
#pragma unroll
  for (int am = 0; am < 2; ++am)
#pragma unroll
    for (int dt = 0; dt < 4; ++dt)
#pragma unroll
      for (int r = 0; r < 4; ++r) {
        const int c = cg * 32 + am * 16 + lg * 4 + r;
        const int d = dh * 64 + dt * 16 + li;
        P[c * C_ + d] = acc[am][dt][r];
      }
  if (mat == 0) {
#pragma unroll
    for (int dt = 0; dt < 2; ++dt) {
      float z = zac[dt];
      z += __shfl_xor(z, 16);
      z += __shfl_xor(z, 32);
      if (lg == 0)
        zpart[((size_t)kc * B_ + b) * C_ + dblk * 32 + dt * 16 + li] = z;
    }
  }
}

// ---------------------------------------------------------------------------
// KB2: cs = (sum_kc part)/Z ; M = cs·qw (bf16), T = cs·qb
// (unchanged from rounds 8-15)
// ---------------------------------------------------------------------------
__global__ __launch_bounds__(256) void kb2_fin(
    const float* __restrict__ part, const float* __restrict__ zpart,
    const float* __restrict__ qw, const float* __restrict__ qb,
    u16* __restrict__ M, float* __restrict__ T) {
  const int b = blockIdx.y;
  const int cs0 = blockIdx.x * 16;
  const int tid = threadIdx.x;
  __shared__ float cs[16][128];
  __shared__ float Zs[128];
  if (tid < 128) {
    float s = 0.f;
    for (int kc = 0; kc < NC; ++kc)
      s += zpart[((size_t)kc * B_ + b) * C_ + tid];
    Zs[tid] = s;
  }
  __syncthreads();
#pragma unroll
  for (int i = 0; i < 8; ++i) {
    const int e = tid + i * 256;
    const int cl = e >> 7, d = e & 127;
    float s = 0.f;
    for (int kc = 0; kc < NC; ++kc)
      s += part[(((size_t)kc * B_ + b) * C_ + (cs0 + cl)) * C_ + d];
    cs[cl][d] = s / Zs[d];
  }
  __syncthreads();
  const int cl = tid >> 4, e0 = (tid & 15) * 8;
  float m[8] = {};
  for (int d = 0; d < 128; ++d) {
    const float cv = cs[cl][d];
    const float* qr = qw + d * C_ + e0;
#pragma unroll
    for (int j = 0; j < 8; ++j) m[j] += cv * qr[j];
  }
  u16* mp = M + ((size_t)b * C_ + cs0 + cl) * C_ + e0;
#pragma unroll
  for (int j = 0; j < 8; ++j) mp[j] = (u16)f2bf(m[j]);
  if (tid < 16) {
    float tv = 0.f;
    for (int d = 0; d < 128; ++d) tv += cs[tid][d] * qb[d];
    T[b * C_ + cs0 + tid] = tv;
  }
}

// ---------------------------------------------------------------------------
// K4 v8: out = M·q_feat + T (fp32).  grid (128, B) = 1024 blocks (~3/CU),
// 256 thr = 4 waves.  Block = ONE [128 c][128 n] subtile: single 32 KB LDS
// stage, ONE barrier, reg-held acc[2][8], single deferred write burst.
// Phase overlap now comes from 3 co-resident blocks per CU (read/compute/
// write phases of different blocks interleave — m114-style TLP) instead of
// intra-block pipelining with 1 block/CU and 8 lockstep barriers.
// Store values bit-identical to r14/r15 (same qt construction, fragments,
// ks order).  Chunked XCD remap: XCD k owns batch k.
// ---------------------------------------------------------------------------
#define K4_LOADS(H_) do {                                                    \
  _Pragma("unroll") for (int i_ = 0; i_ < 8; ++i_)                           \
    xf[i_] = *reinterpret_cast<const f32x4*>(                                \
        qsrc + (size_t)((H_) * 16 + (lane >> 5) * 8 + i_) * N_ +             \
        (lane & 31) * 4);                                                    \
} while (0)

#define K4_XWRITE(H_) do {                                                   \
  const int db_ = w * 32 + (H_) * 16 + (lane >> 5) * 8;                      \
  _Pragma("unroll") for (int k_ = 0; k_ < 4; ++k_) {                         \
    const int n_ = (lane & 31) * 4 + k_;                                     \
    uint4 q_;                                                                \
    q_.x = cvtpk(xf[0][k_], xf[1][k_]);                                      \
    q_.y = cvtpk(xf[2][k_], xf[3][k_]);                                      \
    q_.z = cvtpk(xf[4][k_], xf[5][k_]);                                      \
    q_.w = cvtpk(xf[6][k_], xf[7][k_]);                                      \
    *reinterpret_cast<uint4*>(                                               \
        qt + n_ * SN + (db_ ^ ((n_ & 7) << 3))) = q_;                        \
  }                                                                          \
} while (0)

__global__ __launch_bounds__(256) void k4_out(const u16* __restrict__ M,
                                              const float* __restrict__ T,
                                              const float* __restrict__ q,
                                              float* __restrict__ out) {
  __shared__ u16 qt[SN * C_];  // [n][d] bf16 swizzled, 32 KB

  const int fid = blockIdx.x + blockIdx.y * 128;   // [0,1024)
  const int fid2 = (fid & 7) * 128 + (fid >> 3);   // XCD k -> batch k
  const int b = fid2 >> 7, nc = fid2 & 127;
  const int nb = nc * SN;
  const int tid = threadIdx.x;
  const int w = tid >> 6, lane = tid & 63;
  const int lg = lane >> 4, li = lane & 15;

  // staging source: wave w owns d-rows [w*32, +32), two 16-row halves
  const float* qsrc = q + (size_t)b * C_ * N_ + nb + (size_t)(w * 32) * N_;

  // M fragments (A operand rows c = w*32+ct*16+li) + T (per output row)
  short8 mreg[2][4];
  const u16* Mb = M + (size_t)b * C_ * C_;
#pragma unroll
  for (int ct = 0; ct < 2; ++ct)
#pragma unroll
    for (int ks = 0; ks < 4; ++ks)
      mreg[ct][ks] = *reinterpret_cast<const short8*>(
          Mb + (w * 32 + ct * 16 + li) * C_ + ks * 32 + lg * 8);
  float tcv[2][4];
#pragma unroll
  for (int ct = 0; ct < 2; ++ct)
#pragma unroll
    for (int r = 0; r < 4; ++r)
      tcv[ct][r] = T[b * C_ + w * 32 + ct * 16 + lg * 4 + r];

  // ---- stage: 128x128 fp32 -> bf16 qt, two half-stages ----
  f32x4 xf[8];
  K4_LOADS(0);
  K4_XWRITE(0);
  K4_LOADS(1);
  K4_XWRITE(1);
  __syncthreads();

  // ---- MFMA: D[c][n]; wave w owns c in [w*32,+32), n in [0,128) ----
  f32x4 acc[2][8] = {};  // [ct][nt]
#pragma unroll
  for (int nt = 0; nt < 8; ++nt) {
    const int n = nt * 16 + li;
#pragma unroll
    for (int ks = 0; ks < 4; ++ks) {
      short8 bb = *reinterpret_cast<const short8*>(
          qt + n * SN + ((ks * 32 + lg * 8) ^ ((n & 7) << 3)));
#pragma unroll
      for (int ct = 0; ct < 2; ++ct)
        acc[ct][nt] = __builtin_amdgcn_mfma_f32_16x16x32_bf16(
            mreg[ct][ks], bb, acc[ct][nt], 0, 0, 0);
    }
  }

  // ---- epilogue: single deferred write burst (64 KB/block) ----
#pragma unroll
  for (int ct = 0; ct < 2; ++ct)
#pragma unroll
    for (int r = 0; r < 4; ++r) {
      const int c = w * 32 + ct * 16 + lg * 4 + r;
      float* op = out + ((size_t)b * C_ + c) * N_ + nb;
      const float t = tcv[ct][r];
#pragma unroll
      for (int nt = 0; nt < 8; ++nt)
        op[nt * 16 + li] = acc[ct][nt][r] + t;
    }
}

// ---------------------------------------------------------------------------
extern "C" void kernel_launch(void* const* d_in, const int* in_sizes, int n_in,
                              void* d_out, int out_size, void* d_ws, size_t ws_size,
                              hipStream_t stream) {
  const float* q_feat  = (const float*)d_in[0];
  const float* kv_feat = (const float*)d_in[1];
  const float* q_w = (const float*)d_in[2];
  const float* q_b = (const float*)d_in[3];
  const float* k_w = (const float*)d_in[4];
  const float* k_b = (const float*)d_in[5];
  const float* v_w = (const float*)d_in[6];
  const float* v_b = (const float*)d_in[7];
  float* out = (float*)d_out;

  char* ws = (char*)d_ws;
  const size_t szPart = (size_t)NC * B_ * C_ * C_ * sizeof(float);  // 16 MB
  const size_t szZp   = (size_t)NC * B_ * C_ * sizeof(float);       // 128 KB
  const size_t szWbf  = (size_t)2 * C_ * C_ * sizeof(u16);          // 64 KB
  const size_t szM    = (size_t)B_ * C_ * C_ * sizeof(u16);         // 256 KB

  float* part  = (float*)ws;
  float* zpart = (float*)(ws + szPart);
  u16*   wbf   = (u16*)(ws + szPart + szZp);
  u16*   M     = (u16*)(ws + szPart + szZp + szWbf);
  float* T     = (float*)(ws + szPart + szZp + szWbf + szM);

  k0_wcvt<<<dim3(32), 256, 0, stream>>>(k_w, v_w, wbf);
  ka_projctx<<<dim3(NC, B_), 512, 0, stream>>>(kv_feat, wbf, k_b, v_b, part, zpart);
  kb2_fin<<<dim3(8, B_), 256, 0, stream>>>(part, zpart, q_w, q_b, M, T);
  k4_out<<<dim3(128, B_), 256, 0, stream>>>(M, T, q_feat, out);
}